// Round 5
// baseline (227.899 us; speedup 1.0000x reference)
//
#include <hip/hip_runtime.h>
#include <cstddef>

#define HH 512
#define WW 512
#define BB 8
#define TX 64
#define TY 32

// ws layout (floats):
//   [0..72)      keff_edge  (3*3)*8ch
//   [72..193)    Keff11     11*11
//   [256..1280)  F32-bank (grad filters, 32x32x16 A-frags): 2 tiles x 64 ln x 8 bf16
//                A_t[ch=ln&31][k=(ln>>5)*8+j] = (k<9) ? K_t[k*32+ch] : 0
//   [1280..4096) KT2-bank (kappa x-Toeplitz B-frags): 11 a x 64 lanes x 8 bf16
//                B_a[k=(ln>>4)*8+j][n=ln&15] = kef[a][k-n] if 0<=k-n<=10 else 0
#define F0    256
#define KT0   1280
#define WS_NEEDED_BYTES ((size_t)4096 * 4)

typedef __attribute__((ext_vector_type(8))) short short8;
typedef __attribute__((ext_vector_type(4))) float float4v;
typedef __attribute__((ext_vector_type(2))) float float2v;
typedef __attribute__((ext_vector_type(16))) float float16v;

__device__ inline unsigned short f2bf(float f) {   // fp32 -> bf16 RNE
  unsigned u = __builtin_bit_cast(unsigned, f);
  unsigned r = (u + 0x7FFFu + ((u >> 16) & 1u)) >> 16;
  return (unsigned short)r;
}
__device__ inline float bf2f(unsigned short h) {
  unsigned u = ((unsigned)h) << 16;
  return __builtin_bit_cast(float, u);
}
__device__ inline float2v pmax0(float2v a) {       // packed relu (v_pk_max_f32)
  float2v z = {0.f, 0.f};
  return __builtin_elementwise_max(a, z);
}
__device__ inline float rsum16(float16v cc) {      // sum of relu over 16 accum regs
  float2v s = pmax0(__builtin_shufflevector(cc, cc, 0, 1)) +
              pmax0(__builtin_shufflevector(cc, cc, 2, 3)) +
              pmax0(__builtin_shufflevector(cc, cc, 4, 5)) +
              pmax0(__builtin_shufflevector(cc, cc, 6, 7)) +
              pmax0(__builtin_shufflevector(cc, cc, 8, 9)) +
              pmax0(__builtin_shufflevector(cc, cc, 10, 11)) +
              pmax0(__builtin_shufflevector(cc, cc, 12, 13)) +
              pmax0(__builtin_shufflevector(cc, cc, 14, 15));
  return s[0] + s[1];
}

__global__ __launch_bounds__(256) void precompute_kernels(
    const float* __restrict__ kd,   // (3,3,1,8)
    const float* __restrict__ kp,   // (1,1,8,8)
    const float* __restrict__ k0,   // (5,5,1,8)
    const float* __restrict__ k1,   // (5,5,8,8)
    const float* __restrict__ k2,   // (3,3,8,16)
    const float* __restrict__ kx,   // (3,3,1,32)
    const float* __restrict__ ky,   // (3,3,1,32)
    float* __restrict__ ws) {
  __shared__ float k9[648];
  __shared__ float k2s[72];
  __shared__ float kef[121];
  const int tid = threadIdx.x;

  for (int idx = tid; idx < 72; idx += 256) {
    int c = idx & 7, pq = idx >> 3;
    float s = 0.f;
    for (int c0 = 0; c0 < 8; ++c0) s = fmaf(kd[pq * 8 + c0], kp[c0 * 8 + c], s);
    ws[idx] = s;
  }
  for (int idx = tid; idx < 72; idx += 256) {
    int c1 = idx & 7, tv = idx >> 3;
    float s = 0.f;
    for (int c2 = 0; c2 < 16; ++c2) s += k2[(tv * 8 + c1) * 16 + c2];
    k2s[idx] = s;
  }
  for (int idx = tid; idx < 648; idx += 256) {
    int c1 = idx & 7;
    int ab = idx >> 3;
    int a = ab / 9, b = ab % 9;
    float s = 0.f;
    int plo = a > 4 ? a - 4 : 0, phi = a < 4 ? a : 4;
    int qlo = b > 4 ? b - 4 : 0, qhi = b < 4 ? b : 4;
    for (int p = plo; p <= phi; ++p)
      for (int q = qlo; q <= qhi; ++q) {
        int r = a - p, sx = b - q;
        const float* k0p = &k0[(p * 5 + q) * 8];
        const float* k1p = &k1[((r * 5 + sx) * 8) * 8 + c1];
        for (int c0 = 0; c0 < 8; ++c0) s = fmaf(k0p[c0], k1p[c0 * 8], s);
      }
    k9[idx] = s;
  }
  // F32-bank: grad filters as 32x32x16 A-frags (2 tiles: kx, ky)
  for (int idx = tid; idx < 1024; idx += 256) {
    int t = idx >> 9, ln = (idx >> 3) & 63, j = idx & 7;
    int k = (ln >> 5) * 8 + j;
    int ch = ln & 31;
    float v = 0.f;
    if (k < 9) v = (t == 0) ? kx[k * 32 + ch] : ky[k * 32 + ch];
    ((unsigned short*)ws)[F0 * 2 + idx] = f2bf(v);
  }
  __syncthreads();
  for (int idx = tid; idx < 121; idx += 256) {
    int A = idx / 11, B = idx % 11;
    float s = 0.f;
    int tlo = A > 8 ? A - 8 : 0, thi = A < 2 ? A : 2;
    int vlo = B > 8 ? B - 8 : 0, vhi = B < 2 ? B : 2;
    for (int t = tlo; t <= thi; ++t)
      for (int v = vlo; v <= vhi; ++v) {
        int a = A - t, b = B - v;
        for (int c1 = 0; c1 < 8; ++c1)
          s = fmaf(k9[(a * 9 + b) * 8 + c1], k2s[(t * 3 + v) * 8 + c1], s);
      }
    ws[72 + idx] = s;
    kef[idx] = s;
  }
  __syncthreads();
  // KT2-bank: kappa x-Toeplitz B-frags (bf16), one per y-tap a=0..10.
  for (int idx = tid; idx < 5632; idx += 256) {
    int a = idx >> 9, ln = (idx >> 3) & 63, j = idx & 7;
    int n = ln & 15;
    int k = (ln >> 4) * 8 + j;
    int bb = k - n;
    float v = ((unsigned)bb < 11u) ? kef[a * 11 + bb] : 0.f;
    ((unsigned short*)ws)[KT0 * 2 + idx] = f2bf(v);
  }
}

// ---------------- fused kernel v9: 64x32 tiles, 512 threads -----------------
// R21: TLP reshape with ZERO extra work. Same tile/LDS as v8 (35,328 B x 4
// blocks = 141 KB fits), but 512 threads/block -> 4 blocks x 8 waves = 32
// waves/CU = 8 waves/SIMD (HW cap), 2x v8's TLP. launch_bounds(512,8) pins
// VGPR <= 64 so the allocation holds. Phase partitioning: 1b strides by 8
// waves; phase 2 waves own 4 rows (was 8), combine halves own 2 rows.
__global__ __launch_bounds__(512, 8) void fused(
    const float* __restrict__ u, const float* __restrict__ img,
    const float* __restrict__ kk, const float* __restrict__ sm,
    const float* __restrict__ ws, float* __restrict__ out) {
  // su2: u bf16 ROW-major [58 rows][88 stride]; staged rows by-7..by+39 (47),
  //      cols bx-7..bx+70 (78). Cols 78..87 zero-filled. Rows 47..57 + tail
  //      garbage: only read into discarded C rows. Stride 88 shorts = 11 x 16B
  //      (odd) -> conflict-free b128 reads.
  __shared__ alignas(16) unsigned short su2[58 * 88 + 16];
  __shared__ float si[36 * 71];           // image, rows by-2..by+33, cols bx-2..bx+67
  __shared__ unsigned short sebf[34 * 68];// edges bf16, rows by-1..by+32, cols bx-1..bx+64 (66 used)
  __shared__ float skp[36 * 69];          // kappa*kk, rows by-2..by+33, cols bx-2..bx+65 (68 used)
  __shared__ alignas(16) float skf[72];   // keff_edge cached (broadcast reads)

  const int bx = blockIdx.x * TX, by = blockIdx.y * TY, b = blockIdx.z;
  const int tid = threadIdx.x;
  const float* ub = u + (size_t)b * HH * WW;
  const float* ib = img + (size_t)b * HH * WW;

  const int lane = tid & 63;
  const int wv   = tid >> 6;              // 0..7
  const int q    = lane >> 4;
  const int m    = lane & 15;

  // ---- phase 0: stage (row-major: coalesced global reads, conflict-free LDS) ----
  if (tid < 72) skf[tid] = ws[tid];
  for (int idx = tid; idx < 47 * 78; idx += 512) {
    int r = idx / 78, c = idx % 78;
    int gy = by - 7 + r, gx = bx - 7 + c;
    float v = 0.f;
    if ((unsigned)gy < HH && (unsigned)gx < WW) v = ub[gy * WW + gx];
    su2[r * 88 + c] = f2bf(v);
  }
  for (int idx = tid; idx < 58 * 5; idx += 512) {   // zero cols 78..87, all 58 rows
    int r = idx / 5, c2 = idx % 5;
    *reinterpret_cast<unsigned*>(&su2[r * 88 + 78 + c2 * 2]) = 0u;
  }
  for (int idx = tid; idx < 36 * 70; idx += 512) {
    int i = idx / 70, j = idx % 70;
    int gy = by - 2 + i, gx = bx - 2 + j;
    float v = 0.f;
    if ((unsigned)gy < HH && (unsigned)gx < WW) v = ib[gy * WW + gx];
    si[i * 71 + j] = v;
  }
  __syncthreads();

  // ---- phase 1a: edges on 34 rows x 66 cols (strips of 4), packed channels ----
  for (int idx = tid; idx < 34 * 17; idx += 512) {
    int i = idx % 34, j0 = (idx / 34) * 4;
    float2v acc2[4][4];
    #pragma unroll
    for (int c2 = 0; c2 < 4; ++c2)
      #pragma unroll
      for (int t = 0; t < 4; ++t) acc2[c2][t] = (float2v){0.f, 0.f};
    #pragma unroll
    for (int p = 0; p < 3; ++p) {
      float r[6];
      #pragma unroll
      for (int t = 0; t < 6; ++t) r[t] = si[(i + p) * 71 + j0 + t];
      #pragma unroll
      for (int qq = 0; qq < 3; ++qq) {
        const float* wb = &skf[(p * 3 + qq) * 8];
        float2v w0 = *reinterpret_cast<const float2v*>(wb + 0);
        float2v w1 = *reinterpret_cast<const float2v*>(wb + 2);
        float2v w2 = *reinterpret_cast<const float2v*>(wb + 4);
        float2v w3 = *reinterpret_cast<const float2v*>(wb + 6);
        #pragma unroll
        for (int t = 0; t < 4; ++t) {
          float2v v2 = {r[qq + t], r[qq + t]};
          acc2[0][t] = acc2[0][t] + v2 * w0;
          acc2[1][t] = acc2[1][t] + v2 * w1;
          acc2[2][t] = acc2[2][t] + v2 * w2;
          acc2[3][t] = acc2[3][t] + v2 * w3;
        }
      }
    }
    int gy = by - 1 + i;
    #pragma unroll
    for (int t = 0; t < 4; ++t) {
      int j = j0 + t;
      if (j < 66) {
        int gx = bx - 1 + j;
        float val = 0.f;
        if ((unsigned)gy < HH && (unsigned)gx < WW) {
          float2v e2 = pmax0(acc2[0][t]) + pmax0(acc2[1][t]) +
                       pmax0(acc2[2][t]) + pmax0(acc2[3][t]);
          float e = e2[0] + e2[1];
          val = e / (1.f + e);
        }
        sebf[i * 68 + j] = f2bf(val);
      }
    }
  }

  // ---- phase 1b: kappa via swapped-operand Toeplitz MFMA, 3x5=15 subtiles ----
  {
    const unsigned short* KT = ((const unsigned short*)ws) + KT0 * 2;
    for (int s = wv; s < 15; s += 8) {
      int sty = s / 5, stx = s % 5;
      float4v acc = {0.f, 0.f, 0.f, 0.f};
      const unsigned short* arow = &su2[(sty * 16 + m) * 88 + stx * 16 + q * 8];
      #pragma unroll
      for (int a = 0; a < 11; ++a) {
        short8 bf = *reinterpret_cast<const short8*>(KT + (a * 64 + lane) * 8);
        short8 af = *reinterpret_cast<const short8*>(arow + a * 88);
        acc = __builtin_amdgcn_mfma_f32_16x16x32_bf16(af, bf, acc, 0, 0, 0);
      }
      #pragma unroll
      for (int i = 0; i < 4; ++i) {
        int rl = sty * 16 + q * 4 + i, cl = stx * 16 + m;
        if (rl < 36 && cl < 68) {
          int yy = by - 2 + rl, xx = bx - 2 + cl;
          float v = 0.f;
          if ((unsigned)yy < HH && (unsigned)xx < WW)
            v = acc[i] * kk[(size_t)yy * WW + xx];
          skp[rl * 69 + cl] = v;
        }
      }
    }
  }
  __syncthreads();

  // ---- phase 2: grads via 32x32x16 MFMA + split combine ----
  // Wave wv owns pixel rows wv*4 .. wv*4+3.
  // A (filters): row=ch=lane&31, k=(lane>>5)*8+j (taps; >=9 zero).
  // B (edge window): n=lane&31=col; lanes<32 taps 0..7, lanes>=32 tap 8.
  // C: col=lane&31; lane holds 16 of 32 ch-rows, partner lane^32 the
  // complement -> one shfl_xor(32) finishes the channel sum.
  {
    const unsigned short* F = ((const unsigned short*)ws) + F0 * 2;
    short8 afx = *reinterpret_cast<const short8*>(F + lane * 8);
    short8 afy = *reinterpret_cast<const short8*>(F + (64 + lane) * 8);

    const int c    = lane & 31;
    const int half = lane >> 5;
    const int R0   = wv * 4;              // wave's base pixel row
    const float16v cz = {0.f, 0.f, 0.f, 0.f, 0.f, 0.f, 0.f, 0.f,
                         0.f, 0.f, 0.f, 0.f, 0.f, 0.f, 0.f, 0.f};

    #pragma unroll
    for (int h = 0; h < 2; ++h) {
      const int cl = h * 32 + c;            // pixel col (tile-local, 0..63)
      unsigned short W[9];
      #pragma unroll
      for (int d = 0; d < 3; ++d) {
        const unsigned short* rp = &sebf[(R0 + d) * 68 + cl];
        W[3 * d + 0] = rp[0]; W[3 * d + 1] = rp[1]; W[3 * d + 2] = rp[2];
      }

      float rxv[4], ryv[4];
      #pragma unroll
      for (int r = 0; r < 4; ++r) {
        short8 bv = (short8)0;
        if (half == 0) {
          #pragma unroll
          for (int j = 0; j < 8; ++j) bv[j] = (short)W[j];
        } else {
          bv[0] = (short)W[8];
        }

        float16v cx = __builtin_amdgcn_mfma_f32_32x32x16_bf16(afx, bv, cz, 0, 0, 0);
        float16v cy = __builtin_amdgcn_mfma_f32_32x32x16_bf16(afy, bv, cz, 0, 0, 0);

        float rx = rsum16(cx);
        float ry = rsum16(cy);
        rx += __shfl_xor(rx, 32);
        ry += __shfl_xor(ry, 32);
        rxv[r] = rx; ryv[r] = ry;

        if (r < 3) {
          #pragma unroll
          for (int t = 0; t < 6; ++t) W[t] = W[t + 3];
          const unsigned short* rp = &sebf[(R0 + r + 3) * 68 + cl];
          W[6] = rp[0]; W[7] = rp[1]; W[8] = rp[2];
        }
      }

      // combine: lane half -> rows B..B+1, B = R0 + 2*half, col cl
      {
        const int B = R0 + 2 * half;
        const int gx = bx + cl;

        float kap[2] = {0.f, 0.f};
        #pragma unroll
        for (int ii = 0; ii < 6; ++ii) {
          float rowv[5];
          #pragma unroll
          for (int n = 0; n < 5; ++n) rowv[n] = skp[(B + ii) * 69 + cl + n];
          #pragma unroll
          for (int rr = 0; rr < 2; ++rr) {
            const int m5 = ii - rr;
            if (m5 >= 0 && m5 < 5) {
              #pragma unroll
              for (int n = 0; n < 5; ++n)
                kap[rr] = fmaf(rowv[n], sm[m5 * 5 + n], kap[rr]);
            }
          }
        }

        float ucv[3];
        #pragma unroll
        for (int t = 0; t < 3; ++t) {
          int gy = by + B + t;
          ucv[t] = (gy < HH) ? ub[(size_t)gy * WW + gx] : 0.f;
        }

        #pragma unroll
        for (int rr = 0; rr < 2; ++rr) {
          const int oy = B + rr;
          const int gy = by + oy;
          float uc = ucv[rr];
          float ul = gx > 0 ? ub[(size_t)gy * WW + gx - 1] : 0.f;
          float ud = ucv[rr + 1];          // 0 at gy==HH-1 via guard above
          float ec = bf2f(sebf[(oy + 1) * 68 + cl + 1]);
          float xp = uc - ul;
          float yp = uc - ud;
          out[((size_t)b * HH + gy) * WW + gx] =
              uc + rxv[2 * half + rr] * xp + ryv[2 * half + rr] * yp + ec + kap[rr];
        }
      }
    }
  }
}

// ---------------- Fallback: R3 monolith (used if ws too small) --------------
__global__ __launch_bounds__(256) void forcing_main(
    const float* __restrict__ u, const float* __restrict__ img,
    const float* __restrict__ kx, const float* __restrict__ ky,
    const float* __restrict__ sm, const float* __restrict__ kk,
    const float* __restrict__ ws, float* __restrict__ out) {
  __shared__ float su[46][48];
  __shared__ float si[36][37];
  __shared__ float se[34][35];
  __shared__ float sk[36][37];
  __shared__ float w_edge[72];
  __shared__ float w_kx[288];
  __shared__ float w_ky[288];
  __shared__ float w_k11[124];
  __shared__ float w_sm[28];

  const int bx = blockIdx.x * 32;
  const int by = blockIdx.y * 32;
  const int b  = blockIdx.z;
  const int tid = threadIdx.x;
  const float* ub = u   + (size_t)b * HH * WW;
  const float* ib = img + (size_t)b * HH * WW;

  for (int i = tid; i < 72; i += 256)  w_edge[i] = ws[i];
  for (int i = tid; i < 121; i += 256) w_k11[i]  = ws[72 + i];
  for (int i = tid; i < 288; i += 256) { w_kx[i] = kx[i]; w_ky[i] = ky[i]; }
  if (tid < 25) w_sm[tid] = sm[tid];

  for (int idx = tid; idx < 46 * 46; idx += 256) {
    int i = idx / 46, j = idx % 46;
    int gy = by - 7 + i, gx = bx - 7 + j;
    float v = 0.f;
    if ((unsigned)gy < HH && (unsigned)gx < WW) v = ub[gy * WW + gx];
    su[i][j] = v;
  }
  for (int idx = tid; idx < 36 * 36; idx += 256) {
    int i = idx / 36, j = idx % 36;
    int gy = by - 2 + i, gx = bx - 2 + j;
    float v = 0.f;
    if ((unsigned)gy < HH && (unsigned)gx < WW) v = ib[gy * WW + gx];
    si[i][j] = v;
  }
  __syncthreads();

  for (int idx = tid; idx < 34 * 9; idx += 256) {
    int i = idx / 9, j0 = (idx % 9) * 4;
    float acc[8][4];
    #pragma unroll
    for (int c = 0; c < 8; ++c)
      #pragma unroll
      for (int t = 0; t < 4; ++t) acc[c][t] = 0.f;
    #pragma unroll
    for (int p = 0; p < 3; ++p) {
      float r[6];
      #pragma unroll
      for (int t = 0; t < 6; ++t) r[t] = si[i + p][j0 + t];
      #pragma unroll
      for (int q = 0; q < 3; ++q) {
        const float4 w0 = *reinterpret_cast<const float4*>(&w_edge[(p * 3 + q) * 8]);
        const float4 w1 = *reinterpret_cast<const float4*>(&w_edge[(p * 3 + q) * 8 + 4]);
        #pragma unroll
        for (int t = 0; t < 4; ++t) {
          float v = r[q + t];
          acc[0][t] = fmaf(v, w0.x, acc[0][t]);
          acc[1][t] = fmaf(v, w0.y, acc[1][t]);
          acc[2][t] = fmaf(v, w0.z, acc[2][t]);
          acc[3][t] = fmaf(v, w0.w, acc[3][t]);
          acc[4][t] = fmaf(v, w1.x, acc[4][t]);
          acc[5][t] = fmaf(v, w1.y, acc[5][t]);
          acc[6][t] = fmaf(v, w1.z, acc[6][t]);
          acc[7][t] = fmaf(v, w1.w, acc[7][t]);
        }
      }
    }
    int gy = by - 1 + i;
    #pragma unroll
    for (int t = 0; t < 4; ++t) {
      int j = j0 + t;
      if (j < 34) {
        int gx = bx - 1 + j;
        float val = 0.f;
        if ((unsigned)gy < HH && (unsigned)gx < WW) {
          float e = 0.f;
          #pragma unroll
          for (int c = 0; c < 8; ++c) e += fmaxf(acc[c][t], 0.f);
          val = e / (1.f + e);
        }
        se[i][j] = val;
      }
    }
  }

  for (int idx = tid; idx < 36 * 9; idx += 256) {
    int i = idx / 9, js = (idx % 9) * 4;
    float o0 = 0.f, o1 = 0.f, o2 = 0.f, o3 = 0.f;
    #pragma unroll
    for (int A = 0; A < 11; ++A) {
      const float* row = &su[i + A][js];
      float4 v0 = *reinterpret_cast<const float4*>(row);
      float4 v1 = *reinterpret_cast<const float4*>(row + 4);
      float4 v2 = *reinterpret_cast<const float4*>(row + 8);
      float r[14] = {v0.x, v0.y, v0.z, v0.w, v1.x, v1.y, v1.z, v1.w,
                     v2.x, v2.y, v2.z, v2.w, row[12], row[13]};
      #pragma unroll
      for (int B2 = 0; B2 < 11; ++B2) {
        float w = w_k11[A * 11 + B2];
        o0 = fmaf(r[B2],     w, o0);
        o1 = fmaf(r[B2 + 1], w, o1);
        o2 = fmaf(r[B2 + 2], w, o2);
        o3 = fmaf(r[B2 + 3], w, o3);
      }
    }
    int gy = by - 2 + i;
    float o[4] = {o0, o1, o2, o3};
    #pragma unroll
    for (int t = 0; t < 4; ++t) {
      int gx = bx - 2 + js + t;
      float val = 0.f;
      if ((unsigned)gy < HH && (unsigned)gx < WW) val = o[t] * kk[gy * WW + gx];
      sk[i][js + t] = val;
    }
  }
  __syncthreads();

  {
    const int oy = tid >> 3;
    const int ox = (tid & 7) * 4;
    const int gy = by + oy;
    const int gx = bx + ox;

    float e[3][6];
    #pragma unroll
    for (int p = 0; p < 3; ++p)
      #pragma unroll
      for (int t = 0; t < 6; ++t) e[p][t] = se[oy + p][ox + t];

    const float4* wx4 = reinterpret_cast<const float4*>(w_kx);
    const float4* wy4 = reinterpret_cast<const float4*>(w_ky);

    float gxa[4] = {0.f, 0.f, 0.f, 0.f};
    float gya[4] = {0.f, 0.f, 0.f, 0.f};
    #pragma unroll
    for (int cq = 0; cq < 8; ++cq) {
      float sx[4][4], sy[4][4];
      #pragma unroll
      for (int cc = 0; cc < 4; ++cc)
        #pragma unroll
        for (int t = 0; t < 4; ++t) { sx[cc][t] = 0.f; sy[cc][t] = 0.f; }
      #pragma unroll
      for (int p = 0; p < 3; ++p)
        #pragma unroll
        for (int q = 0; q < 3; ++q) {
          float4 wx = wx4[(p * 3 + q) * 8 + cq];
          float4 wy = wy4[(p * 3 + q) * 8 + cq];
          #pragma unroll
          for (int t = 0; t < 4; ++t) {
            float evv = e[p][q + t];
            sx[0][t] = fmaf(evv, wx.x, sx[0][t]);
            sx[1][t] = fmaf(evv, wx.y, sx[1][t]);
            sx[2][t] = fmaf(evv, wx.z, sx[2][t]);
            sx[3][t] = fmaf(evv, wx.w, sx[3][t]);
            sy[0][t] = fmaf(evv, wy.x, sy[0][t]);
            sy[1][t] = fmaf(evv, wy.y, sy[1][t]);
            sy[2][t] = fmaf(evv, wy.z, sy[2][t]);
            sy[3][t] = fmaf(evv, wy.w, sy[3][t]);
          }
        }
      #pragma unroll
      for (int cc = 0; cc < 4; ++cc)
        #pragma unroll
        for (int t = 0; t < 4; ++t) {
          gxa[t] += fmaxf(sx[cc][t], 0.f);
          gya[t] += fmaxf(sy[cc][t], 0.f);
        }
    }

    float res[4];
    #pragma unroll
    for (int t = 0; t < 4; ++t) {
      float kap = 0.f;
      #pragma unroll
      for (int m = 0; m < 5; ++m)
        #pragma unroll
        for (int n = 0; n < 5; ++n)
          kap = fmaf(sk[oy + m][ox + t + n], w_sm[m * 5 + n], kap);

      float uc = su[oy + 7][ox + 7 + t];
      float xp = uc - su[oy + 7][ox + 6 + t];
      float yp = uc - su[oy + 8][ox + 7 + t];
      float ec = se[oy + 1][ox + 1 + t];
      res[t] = uc + gxa[t] * xp + gya[t] * yp + ec + kap;
    }

    float4 r4 = make_float4(res[0], res[1], res[2], res[3]);
    *reinterpret_cast<float4*>(&out[((size_t)b * HH + gy) * WW + gx]) = r4;
  }
}

extern "C" void kernel_launch(void* const* d_in, const int* in_sizes, int n_in,
                              void* d_out, int out_size, void* d_ws, size_t ws_size,
                              hipStream_t stream) {
  const float* u   = (const float*)d_in[0];
  const float* img = (const float*)d_in[1];
  const float* kx  = (const float*)d_in[2];
  const float* ky  = (const float*)d_in[3];
  const float* kd  = (const float*)d_in[4];
  const float* kp  = (const float*)d_in[5];
  const float* k0  = (const float*)d_in[6];
  const float* k1  = (const float*)d_in[7];
  const float* k2  = (const float*)d_in[8];
  const float* sm  = (const float*)d_in[9];
  const float* kk  = (const float*)d_in[10];
  float* out = (float*)d_out;
  float* ws  = (float*)d_ws;

  precompute_kernels<<<1, 256, 0, stream>>>(kd, kp, k0, k1, k2, kx, ky, ws);
  if (ws != nullptr && ws_size >= WS_NEEDED_BYTES) {
    dim3 grid(WW / TX, HH / TY, BB);
    fused<<<grid, 512, 0, stream>>>(u, img, kk, sm, ws, out);
  } else {
    dim3 grid(WW / 32, HH / 32, BB);
    forcing_main<<<grid, 256, 0, stream>>>(u, img, kx, ky, sm, kk, ws, out);
  }
}

// Round 6
// 133.648 us; speedup vs baseline: 1.7052x; 1.7052x over previous
//
#include <hip/hip_runtime.h>
#include <cstddef>

#define HH 512
#define WW 512
#define BB 8
#define TX 64
#define TY 32

// ws layout (floats):
//   [0..72)      keff_edge  (3*3)*8ch
//   [72..193)    Keff11     11*11
//   [256..1280)  F32-bank (grad filters, 32x32x16 A-frags): 2 tiles x 64 ln x 8 bf16
//                A_t[ch=ln&31][k=(ln>>5)*8+j] = (k<9) ? K_t[k*32+ch] : 0
//   [1280..4096) KT2-bank (kappa x-Toeplitz B-frags): 11 a x 64 lanes x 8 bf16
//                B_a[k=(ln>>4)*8+j][n=ln&15] = kef[a][k-n] if 0<=k-n<=10 else 0
#define F0    256
#define KT0   1280
#define WS_NEEDED_BYTES ((size_t)4096 * 4)

typedef __attribute__((ext_vector_type(8))) short short8;
typedef __attribute__((ext_vector_type(4))) float float4v;
typedef __attribute__((ext_vector_type(2))) float float2v;
typedef __attribute__((ext_vector_type(16))) float float16v;

__device__ inline unsigned short f2bf(float f) {   // fp32 -> bf16 RNE
  unsigned u = __builtin_bit_cast(unsigned, f);
  unsigned r = (u + 0x7FFFu + ((u >> 16) & 1u)) >> 16;
  return (unsigned short)r;
}
__device__ inline float bf2f(unsigned short h) {
  unsigned u = ((unsigned)h) << 16;
  return __builtin_bit_cast(float, u);
}
__device__ inline float2v pmax0(float2v a) {       // packed relu (v_pk_max_f32)
  float2v z = {0.f, 0.f};
  return __builtin_elementwise_max(a, z);
}
__device__ inline float rsum16(float16v cc) {      // sum of relu over 16 accum regs
  float2v s = pmax0(__builtin_shufflevector(cc, cc, 0, 1)) +
              pmax0(__builtin_shufflevector(cc, cc, 2, 3)) +
              pmax0(__builtin_shufflevector(cc, cc, 4, 5)) +
              pmax0(__builtin_shufflevector(cc, cc, 6, 7)) +
              pmax0(__builtin_shufflevector(cc, cc, 8, 9)) +
              pmax0(__builtin_shufflevector(cc, cc, 10, 11)) +
              pmax0(__builtin_shufflevector(cc, cc, 12, 13)) +
              pmax0(__builtin_shufflevector(cc, cc, 14, 15));
  return s[0] + s[1];
}

__global__ __launch_bounds__(256) void precompute_kernels(
    const float* __restrict__ kd,   // (3,3,1,8)
    const float* __restrict__ kp,   // (1,1,8,8)
    const float* __restrict__ k0,   // (5,5,1,8)
    const float* __restrict__ k1,   // (5,5,8,8)
    const float* __restrict__ k2,   // (3,3,8,16)
    const float* __restrict__ kx,   // (3,3,1,32)
    const float* __restrict__ ky,   // (3,3,1,32)
    float* __restrict__ ws) {
  __shared__ float k9[648];
  __shared__ float k2s[72];
  __shared__ float kef[121];
  const int tid = threadIdx.x;

  for (int idx = tid; idx < 72; idx += 256) {
    int c = idx & 7, pq = idx >> 3;
    float s = 0.f;
    for (int c0 = 0; c0 < 8; ++c0) s = fmaf(kd[pq * 8 + c0], kp[c0 * 8 + c], s);
    ws[idx] = s;
  }
  for (int idx = tid; idx < 72; idx += 256) {
    int c1 = idx & 7, tv = idx >> 3;
    float s = 0.f;
    for (int c2 = 0; c2 < 16; ++c2) s += k2[(tv * 8 + c1) * 16 + c2];
    k2s[idx] = s;
  }
  for (int idx = tid; idx < 648; idx += 256) {
    int c1 = idx & 7;
    int ab = idx >> 3;
    int a = ab / 9, b = ab % 9;
    float s = 0.f;
    int plo = a > 4 ? a - 4 : 0, phi = a < 4 ? a : 4;
    int qlo = b > 4 ? b - 4 : 0, qhi = b < 4 ? b : 4;
    for (int p = plo; p <= phi; ++p)
      for (int q = qlo; q <= qhi; ++q) {
        int r = a - p, sx = b - q;
        const float* k0p = &k0[(p * 5 + q) * 8];
        const float* k1p = &k1[((r * 5 + sx) * 8) * 8 + c1];
        for (int c0 = 0; c0 < 8; ++c0) s = fmaf(k0p[c0], k1p[c0 * 8], s);
      }
    k9[idx] = s;
  }
  // F32-bank: grad filters as 32x32x16 A-frags (2 tiles: kx, ky)
  for (int idx = tid; idx < 1024; idx += 256) {
    int t = idx >> 9, ln = (idx >> 3) & 63, j = idx & 7;
    int k = (ln >> 5) * 8 + j;
    int ch = ln & 31;
    float v = 0.f;
    if (k < 9) v = (t == 0) ? kx[k * 32 + ch] : ky[k * 32 + ch];
    ((unsigned short*)ws)[F0 * 2 + idx] = f2bf(v);
  }
  __syncthreads();
  for (int idx = tid; idx < 121; idx += 256) {
    int A = idx / 11, B = idx % 11;
    float s = 0.f;
    int tlo = A > 8 ? A - 8 : 0, thi = A < 2 ? A : 2;
    int vlo = B > 8 ? B - 8 : 0, vhi = B < 2 ? B : 2;
    for (int t = tlo; t <= thi; ++t)
      for (int v = vlo; v <= vhi; ++v) {
        int a = A - t, b = B - v;
        for (int c1 = 0; c1 < 8; ++c1)
          s = fmaf(k9[(a * 9 + b) * 8 + c1], k2s[(t * 3 + v) * 8 + c1], s);
      }
    ws[72 + idx] = s;
    kef[idx] = s;
  }
  __syncthreads();
  // KT2-bank: kappa x-Toeplitz B-frags (bf16), one per y-tap a=0..10.
  for (int idx = tid; idx < 5632; idx += 256) {
    int a = idx >> 9, ln = (idx >> 3) & 63, j = idx & 7;
    int n = ln & 15;
    int k = (ln >> 4) * 8 + j;
    int bb = k - n;
    float v = ((unsigned)bb < 11u) ? kef[a * 11 + bb] : 0.f;
    ((unsigned short*)ws)[KT0 * 2 + idx] = f2bf(v);
  }
}

// ---------------- fused kernel v10: 64x32 tiles, 512 threads ----------------
// R22: retry R21's TLP reshape WITHOUT the VGPR clamp. R21's launch_bounds
// (512,8) forced VGPR=32 -> scratch spill (FETCH 19->296MB). Here: plain
// launch_bounds(512); per-thread state is strictly smaller than v8's (which
// compiled to 64 VGPR at 256 threads), and phase 2 sequences the two MFMAs
// through ONE f32x16 accumulator (cx retires into rx before cy allocates).
// If VGPR <= 64: 4 blocks x 8 waves = 32 waves/CU (2x v8 TLP), same work.
__global__ __launch_bounds__(512) void fused(
    const float* __restrict__ u, const float* __restrict__ img,
    const float* __restrict__ kk, const float* __restrict__ sm,
    const float* __restrict__ ws, float* __restrict__ out) {
  // su2: u bf16 ROW-major [58 rows][88 stride]; staged rows by-7..by+39 (47),
  //      cols bx-7..bx+70 (78). Cols 78..87 zero-filled. Rows 47..57 + tail
  //      garbage: only read into discarded C rows. Stride 88 shorts = 11 x 16B
  //      (odd) -> conflict-free b128 reads.
  __shared__ alignas(16) unsigned short su2[58 * 88 + 16];
  __shared__ float si[36 * 71];           // image, rows by-2..by+33, cols bx-2..bx+67
  __shared__ unsigned short sebf[34 * 68];// edges bf16, rows by-1..by+32, cols bx-1..bx+64 (66 used)
  __shared__ float skp[36 * 69];          // kappa*kk, rows by-2..by+33, cols bx-2..bx+65 (68 used)
  __shared__ alignas(16) float skf[72];   // keff_edge cached (broadcast reads)

  const int bx = blockIdx.x * TX, by = blockIdx.y * TY, b = blockIdx.z;
  const int tid = threadIdx.x;
  const float* ub = u + (size_t)b * HH * WW;
  const float* ib = img + (size_t)b * HH * WW;

  const int lane = tid & 63;
  const int wv   = tid >> 6;              // 0..7
  const int q    = lane >> 4;
  const int m    = lane & 15;

  // ---- phase 0: stage (row-major: coalesced global reads, conflict-free LDS) ----
  if (tid < 72) skf[tid] = ws[tid];
  for (int idx = tid; idx < 47 * 78; idx += 512) {
    int r = idx / 78, c = idx % 78;
    int gy = by - 7 + r, gx = bx - 7 + c;
    float v = 0.f;
    if ((unsigned)gy < HH && (unsigned)gx < WW) v = ub[gy * WW + gx];
    su2[r * 88 + c] = f2bf(v);
  }
  for (int idx = tid; idx < 58 * 5; idx += 512) {   // zero cols 78..87, all 58 rows
    int r = idx / 5, c2 = idx % 5;
    *reinterpret_cast<unsigned*>(&su2[r * 88 + 78 + c2 * 2]) = 0u;
  }
  for (int idx = tid; idx < 36 * 70; idx += 512) {
    int i = idx / 70, j = idx % 70;
    int gy = by - 2 + i, gx = bx - 2 + j;
    float v = 0.f;
    if ((unsigned)gy < HH && (unsigned)gx < WW) v = ib[gy * WW + gx];
    si[i * 71 + j] = v;
  }
  __syncthreads();

  // ---- phase 1a: edges on 34 rows x 66 cols (strips of 4), packed channels ----
  for (int idx = tid; idx < 34 * 17; idx += 512) {
    int i = idx % 34, j0 = (idx / 34) * 4;
    float2v acc2[4][4];
    #pragma unroll
    for (int c2 = 0; c2 < 4; ++c2)
      #pragma unroll
      for (int t = 0; t < 4; ++t) acc2[c2][t] = (float2v){0.f, 0.f};
    #pragma unroll
    for (int p = 0; p < 3; ++p) {
      float r[6];
      #pragma unroll
      for (int t = 0; t < 6; ++t) r[t] = si[(i + p) * 71 + j0 + t];
      #pragma unroll
      for (int qq = 0; qq < 3; ++qq) {
        const float* wb = &skf[(p * 3 + qq) * 8];
        float2v w0 = *reinterpret_cast<const float2v*>(wb + 0);
        float2v w1 = *reinterpret_cast<const float2v*>(wb + 2);
        float2v w2 = *reinterpret_cast<const float2v*>(wb + 4);
        float2v w3 = *reinterpret_cast<const float2v*>(wb + 6);
        #pragma unroll
        for (int t = 0; t < 4; ++t) {
          float2v v2 = {r[qq + t], r[qq + t]};
          acc2[0][t] = acc2[0][t] + v2 * w0;
          acc2[1][t] = acc2[1][t] + v2 * w1;
          acc2[2][t] = acc2[2][t] + v2 * w2;
          acc2[3][t] = acc2[3][t] + v2 * w3;
        }
      }
    }
    int gy = by - 1 + i;
    #pragma unroll
    for (int t = 0; t < 4; ++t) {
      int j = j0 + t;
      if (j < 66) {
        int gx = bx - 1 + j;
        float val = 0.f;
        if ((unsigned)gy < HH && (unsigned)gx < WW) {
          float2v e2 = pmax0(acc2[0][t]) + pmax0(acc2[1][t]) +
                       pmax0(acc2[2][t]) + pmax0(acc2[3][t]);
          float e = e2[0] + e2[1];
          val = e / (1.f + e);
        }
        sebf[i * 68 + j] = f2bf(val);
      }
    }
  }

  // ---- phase 1b: kappa via swapped-operand Toeplitz MFMA, 3x5=15 subtiles ----
  {
    const unsigned short* KT = ((const unsigned short*)ws) + KT0 * 2;
    for (int s = wv; s < 15; s += 8) {
      int sty = s / 5, stx = s % 5;
      float4v acc = {0.f, 0.f, 0.f, 0.f};
      const unsigned short* arow = &su2[(sty * 16 + m) * 88 + stx * 16 + q * 8];
      #pragma unroll
      for (int a = 0; a < 11; ++a) {
        short8 bf = *reinterpret_cast<const short8*>(KT + (a * 64 + lane) * 8);
        short8 af = *reinterpret_cast<const short8*>(arow + a * 88);
        acc = __builtin_amdgcn_mfma_f32_16x16x32_bf16(af, bf, acc, 0, 0, 0);
      }
      #pragma unroll
      for (int i = 0; i < 4; ++i) {
        int rl = sty * 16 + q * 4 + i, cl = stx * 16 + m;
        if (rl < 36 && cl < 68) {
          int yy = by - 2 + rl, xx = bx - 2 + cl;
          float v = 0.f;
          if ((unsigned)yy < HH && (unsigned)xx < WW)
            v = acc[i] * kk[(size_t)yy * WW + xx];
          skp[rl * 69 + cl] = v;
        }
      }
    }
  }
  __syncthreads();

  // ---- phase 2: grads via 32x32x16 MFMA + split combine ----
  // Wave wv owns pixel rows wv*4 .. wv*4+3.
  // A (filters): row=ch=lane&31, k=(lane>>5)*8+j (taps; >=9 zero).
  // B (edge window): n=lane&31=col; lanes<32 taps 0..7, lanes>=32 tap 8.
  // C: col=lane&31; lane holds 16 of 32 ch-rows, partner lane^32 the
  // complement -> one shfl_xor(32) finishes the channel sum.
  {
    const unsigned short* F = ((const unsigned short*)ws) + F0 * 2;
    short8 afx = *reinterpret_cast<const short8*>(F + lane * 8);
    short8 afy = *reinterpret_cast<const short8*>(F + (64 + lane) * 8);

    const int c    = lane & 31;
    const int half = lane >> 5;
    const int R0   = wv * 4;              // wave's base pixel row

    #pragma unroll
    for (int h = 0; h < 2; ++h) {
      const int cl = h * 32 + c;            // pixel col (tile-local, 0..63)
      unsigned short W[9];
      #pragma unroll
      for (int d = 0; d < 3; ++d) {
        const unsigned short* rp = &sebf[(R0 + d) * 68 + cl];
        W[3 * d + 0] = rp[0]; W[3 * d + 1] = rp[1]; W[3 * d + 2] = rp[2];
      }

      float rxv[4], ryv[4];
      #pragma unroll
      for (int r = 0; r < 4; ++r) {
        short8 bv = (short8)0;
        if (half == 0) {
          #pragma unroll
          for (int j = 0; j < 8; ++j) bv[j] = (short)W[j];
        } else {
          bv[0] = (short)W[8];
        }

        // sequence through ONE accumulator: cx retires before cy allocates
        float16v cacc = {0.f, 0.f, 0.f, 0.f, 0.f, 0.f, 0.f, 0.f,
                         0.f, 0.f, 0.f, 0.f, 0.f, 0.f, 0.f, 0.f};
        cacc = __builtin_amdgcn_mfma_f32_32x32x16_bf16(afx, bv, cacc, 0, 0, 0);
        float rx = rsum16(cacc);
        cacc = (float16v){0.f, 0.f, 0.f, 0.f, 0.f, 0.f, 0.f, 0.f,
                          0.f, 0.f, 0.f, 0.f, 0.f, 0.f, 0.f, 0.f};
        cacc = __builtin_amdgcn_mfma_f32_32x32x16_bf16(afy, bv, cacc, 0, 0, 0);
        float ry = rsum16(cacc);

        rx += __shfl_xor(rx, 32);
        ry += __shfl_xor(ry, 32);
        rxv[r] = rx; ryv[r] = ry;

        if (r < 3) {
          #pragma unroll
          for (int t = 0; t < 6; ++t) W[t] = W[t + 3];
          const unsigned short* rp = &sebf[(R0 + r + 3) * 68 + cl];
          W[6] = rp[0]; W[7] = rp[1]; W[8] = rp[2];
        }
      }

      // combine: lane half -> rows B..B+1, B = R0 + 2*half, col cl
      {
        const int B = R0 + 2 * half;
        const int gx = bx + cl;

        float kap[2] = {0.f, 0.f};
        #pragma unroll
        for (int ii = 0; ii < 6; ++ii) {
          float rowv[5];
          #pragma unroll
          for (int n = 0; n < 5; ++n) rowv[n] = skp[(B + ii) * 69 + cl + n];
          #pragma unroll
          for (int rr = 0; rr < 2; ++rr) {
            const int m5 = ii - rr;
            if (m5 >= 0 && m5 < 5) {
              #pragma unroll
              for (int n = 0; n < 5; ++n)
                kap[rr] = fmaf(rowv[n], sm[m5 * 5 + n], kap[rr]);
            }
          }
        }

        float ucv[3];
        #pragma unroll
        for (int t = 0; t < 3; ++t) {
          int gy = by + B + t;
          ucv[t] = (gy < HH) ? ub[(size_t)gy * WW + gx] : 0.f;
        }

        #pragma unroll
        for (int rr = 0; rr < 2; ++rr) {
          const int oy = B + rr;
          const int gy = by + oy;
          float uc = ucv[rr];
          float ul = gx > 0 ? ub[(size_t)gy * WW + gx - 1] : 0.f;
          float ud = ucv[rr + 1];          // 0 at gy==HH-1 via guard above
          float ec = bf2f(sebf[(oy + 1) * 68 + cl + 1]);
          float xp = uc - ul;
          float yp = uc - ud;
          out[((size_t)b * HH + gy) * WW + gx] =
              uc + rxv[2 * half + rr] * xp + ryv[2 * half + rr] * yp + ec + kap[rr];
        }
      }
    }
  }
}

// ---------------- Fallback: R3 monolith (used if ws too small) --------------
__global__ __launch_bounds__(256) void forcing_main(
    const float* __restrict__ u, const float* __restrict__ img,
    const float* __restrict__ kx, const float* __restrict__ ky,
    const float* __restrict__ sm, const float* __restrict__ kk,
    const float* __restrict__ ws, float* __restrict__ out) {
  __shared__ float su[46][48];
  __shared__ float si[36][37];
  __shared__ float se[34][35];
  __shared__ float sk[36][37];
  __shared__ float w_edge[72];
  __shared__ float w_kx[288];
  __shared__ float w_ky[288];
  __shared__ float w_k11[124];
  __shared__ float w_sm[28];

  const int bx = blockIdx.x * 32;
  const int by = blockIdx.y * 32;
  const int b  = blockIdx.z;
  const int tid = threadIdx.x;
  const float* ub = u   + (size_t)b * HH * WW;
  const float* ib = img + (size_t)b * HH * WW;

  for (int i = tid; i < 72; i += 256)  w_edge[i] = ws[i];
  for (int i = tid; i < 121; i += 256) w_k11[i]  = ws[72 + i];
  for (int i = tid; i < 288; i += 256) { w_kx[i] = kx[i]; w_ky[i] = ky[i]; }
  if (tid < 25) w_sm[tid] = sm[tid];

  for (int idx = tid; idx < 46 * 46; idx += 256) {
    int i = idx / 46, j = idx % 46;
    int gy = by - 7 + i, gx = bx - 7 + j;
    float v = 0.f;
    if ((unsigned)gy < HH && (unsigned)gx < WW) v = ub[gy * WW + gx];
    su[i][j] = v;
  }
  for (int idx = tid; idx < 36 * 36; idx += 256) {
    int i = idx / 36, j = idx % 36;
    int gy = by - 2 + i, gx = bx - 2 + j;
    float v = 0.f;
    if ((unsigned)gy < HH && (unsigned)gx < WW) v = ib[gy * WW + gx];
    si[i][j] = v;
  }
  __syncthreads();

  for (int idx = tid; idx < 34 * 9; idx += 256) {
    int i = idx / 9, j0 = (idx % 9) * 4;
    float acc[8][4];
    #pragma unroll
    for (int c = 0; c < 8; ++c)
      #pragma unroll
      for (int t = 0; t < 4; ++t) acc[c][t] = 0.f;
    #pragma unroll
    for (int p = 0; p < 3; ++p) {
      float r[6];
      #pragma unroll
      for (int t = 0; t < 6; ++t) r[t] = si[i + p][j0 + t];
      #pragma unroll
      for (int q = 0; q < 3; ++q) {
        const float4 w0 = *reinterpret_cast<const float4*>(&w_edge[(p * 3 + q) * 8]);
        const float4 w1 = *reinterpret_cast<const float4*>(&w_edge[(p * 3 + q) * 8 + 4]);
        #pragma unroll
        for (int t = 0; t < 4; ++t) {
          float v = r[q + t];
          acc[0][t] = fmaf(v, w0.x, acc[0][t]);
          acc[1][t] = fmaf(v, w0.y, acc[1][t]);
          acc[2][t] = fmaf(v, w0.z, acc[2][t]);
          acc[3][t] = fmaf(v, w0.w, acc[3][t]);
          acc[4][t] = fmaf(v, w1.x, acc[4][t]);
          acc[5][t] = fmaf(v, w1.y, acc[5][t]);
          acc[6][t] = fmaf(v, w1.z, acc[6][t]);
          acc[7][t] = fmaf(v, w1.w, acc[7][t]);
        }
      }
    }
    int gy = by - 1 + i;
    #pragma unroll
    for (int t = 0; t < 4; ++t) {
      int j = j0 + t;
      if (j < 34) {
        int gx = bx - 1 + j;
        float val = 0.f;
        if ((unsigned)gy < HH && (unsigned)gx < WW) {
          float e = 0.f;
          #pragma unroll
          for (int c = 0; c < 8; ++c) e += fmaxf(acc[c][t], 0.f);
          val = e / (1.f + e);
        }
        se[i][j] = val;
      }
    }
  }

  for (int idx = tid; idx < 36 * 9; idx += 256) {
    int i = idx / 9, js = (idx % 9) * 4;
    float o0 = 0.f, o1 = 0.f, o2 = 0.f, o3 = 0.f;
    #pragma unroll
    for (int A = 0; A < 11; ++A) {
      const float* row = &su[i + A][js];
      float4 v0 = *reinterpret_cast<const float4*>(row);
      float4 v1 = *reinterpret_cast<const float4*>(row + 4);
      float4 v2 = *reinterpret_cast<const float4*>(row + 8);
      float r[14] = {v0.x, v0.y, v0.z, v0.w, v1.x, v1.y, v1.z, v1.w,
                     v2.x, v2.y, v2.z, v2.w, row[12], row[13]};
      #pragma unroll
      for (int B2 = 0; B2 < 11; ++B2) {
        float w = w_k11[A * 11 + B2];
        o0 = fmaf(r[B2],     w, o0);
        o1 = fmaf(r[B2 + 1], w, o1);
        o2 = fmaf(r[B2 + 2], w, o2);
        o3 = fmaf(r[B2 + 3], w, o3);
      }
    }
    int gy = by - 2 + i;
    float o[4] = {o0, o1, o2, o3};
    #pragma unroll
    for (int t = 0; t < 4; ++t) {
      int gx = bx - 2 + js + t;
      float val = 0.f;
      if ((unsigned)gy < HH && (unsigned)gx < WW) val = o[t] * kk[gy * WW + gx];
      sk[i][js + t] = val;
    }
  }
  __syncthreads();

  {
    const int oy = tid >> 3;
    const int ox = (tid & 7) * 4;
    const int gy = by + oy;
    const int gx = bx + ox;

    float e[3][6];
    #pragma unroll
    for (int p = 0; p < 3; ++p)
      #pragma unroll
      for (int t = 0; t < 6; ++t) e[p][t] = se[oy + p][ox + t];

    const float4* wx4 = reinterpret_cast<const float4*>(w_kx);
    const float4* wy4 = reinterpret_cast<const float4*>(w_ky);

    float gxa[4] = {0.f, 0.f, 0.f, 0.f};
    float gya[4] = {0.f, 0.f, 0.f, 0.f};
    #pragma unroll
    for (int cq = 0; cq < 8; ++cq) {
      float sx[4][4], sy[4][4];
      #pragma unroll
      for (int cc = 0; cc < 4; ++cc)
        #pragma unroll
        for (int t = 0; t < 4; ++t) { sx[cc][t] = 0.f; sy[cc][t] = 0.f; }
      #pragma unroll
      for (int p = 0; p < 3; ++p)
        #pragma unroll
        for (int q = 0; q < 3; ++q) {
          float4 wx = wx4[(p * 3 + q) * 8 + cq];
          float4 wy = wy4[(p * 3 + q) * 8 + cq];
          #pragma unroll
          for (int t = 0; t < 4; ++t) {
            float evv = e[p][q + t];
            sx[0][t] = fmaf(evv, wx.x, sx[0][t]);
            sx[1][t] = fmaf(evv, wx.y, sx[1][t]);
            sx[2][t] = fmaf(evv, wx.z, sx[2][t]);
            sx[3][t] = fmaf(evv, wx.w, sx[3][t]);
            sy[0][t] = fmaf(evv, wy.x, sy[0][t]);
            sy[1][t] = fmaf(evv, wy.y, sy[1][t]);
            sy[2][t] = fmaf(evv, wy.z, sy[2][t]);
            sy[3][t] = fmaf(evv, wy.w, sy[3][t]);
          }
        }
      #pragma unroll
      for (int cc = 0; cc < 4; ++cc)
        #pragma unroll
        for (int t = 0; t < 4; ++t) {
          gxa[t] += fmaxf(sx[cc][t], 0.f);
          gya[t] += fmaxf(sy[cc][t], 0.f);
        }
    }

    float res[4];
    #pragma unroll
    for (int t = 0; t < 4; ++t) {
      float kap = 0.f;
      #pragma unroll
      for (int m = 0; m < 5; ++m)
        #pragma unroll
        for (int n = 0; n < 5; ++n)
          kap = fmaf(sk[oy + m][ox + t + n], w_sm[m * 5 + n], kap);

      float uc = su[oy + 7][ox + 7 + t];
      float xp = uc - su[oy + 7][ox + 6 + t];
      float yp = uc - su[oy + 8][ox + 7 + t];
      float ec = se[oy + 1][ox + 1 + t];
      res[t] = uc + gxa[t] * xp + gya[t] * yp + ec + kap;
    }

    float4 r4 = make_float4(res[0], res[1], res[2], res[3]);
    *reinterpret_cast<float4*>(&out[((size_t)b * HH + gy) * WW + gx]) = r4;
  }
}

extern "C" void kernel_launch(void* const* d_in, const int* in_sizes, int n_in,
                              void* d_out, int out_size, void* d_ws, size_t ws_size,
                              hipStream_t stream) {
  const float* u   = (const float*)d_in[0];
  const float* img = (const float*)d_in[1];
  const float* kx  = (const float*)d_in[2];
  const float* ky  = (const float*)d_in[3];
  const float* kd  = (const float*)d_in[4];
  const float* kp  = (const float*)d_in[5];
  const float* k0  = (const float*)d_in[6];
  const float* k1  = (const float*)d_in[7];
  const float* k2  = (const float*)d_in[8];
  const float* sm  = (const float*)d_in[9];
  const float* kk  = (const float*)d_in[10];
  float* out = (float*)d_out;
  float* ws  = (float*)d_ws;

  precompute_kernels<<<1, 256, 0, stream>>>(kd, kp, k0, k1, k2, kx, ky, ws);
  if (ws != nullptr && ws_size >= WS_NEEDED_BYTES) {
    dim3 grid(WW / TX, HH / TY, BB);
    fused<<<grid, 512, 0, stream>>>(u, img, kk, sm, ws, out);
  } else {
    dim3 grid(WW / 32, HH / 32, BB);
    forcing_main<<<grid, 256, 0, stream>>>(u, img, kx, ky, sm, kk, ws, out);
  }
}